// Round 2
// baseline (40.062 us; speedup 1.0000x reference)
//
#include <hip/hip_runtime.h>
#include <hip/hip_bf16.h>

#define B_DIM 64
#define N_TOT 2048
#define M_DIM 64
#define O_DIM 128
#define NT 8   // neurons per block

typedef __bf16 bf16x8 __attribute__((ext_vector_type(8)));
typedef float f32x4 __attribute__((ext_vector_type(4)));

__device__ __forceinline__ unsigned short f2bf(float f) {
    union { float f; unsigned int u; } v;
    v.f = f;
    unsigned int r = v.u + 0x7fffu + ((v.u >> 16) & 1u);  // round-to-nearest-even
    return (unsigned short)(r >> 16);
}

// Grid 512 = 256 nblk x 2 b-halves. Block 512 thr (8 waves), wave w -> neuron w,
// rows bh*32..+31. LDS = one 32-k-wide W buffer (64 KiB) -> 2 blocks/CU,
// 16 waves/CU. Two stage/compute rounds over k.
__global__ __launch_bounds__(512, 4) void superlinear_mfma(
    const float* __restrict__ x, const float* __restrict__ w1,
    const float* __restrict__ b1, float* __restrict__ out)
{
    // bf16 W k-chunk, logical [nn][o][k32] (k innermost), XOR-swizzled. 64 KiB.
    __shared__ unsigned char wlds[NT * O_DIM * 32 * 2];

    const int tid  = threadIdx.x;
    const int lane = tid & 63;
    const int wave = tid >> 6;

    // XCD-aware swizzle over 512 blocks (512 % 8 == 0 -> simple form is bijective).
    // Consecutive swz on one XCD => both b-halves of an nblk share that XCD's L2.
    const int bid  = blockIdx.x;
    const int swz  = (bid & 7) * 64 + (bid >> 3);
    const int nblk = swz >> 1;
    const int bh   = swz & 1;
    const int n0   = nblk * NT;

    const int nn  = wave;        // neuron owned by this wave
    const int n   = n0 + nn;
    const int col = lane & 15;   // o (and x-row) index within 16-tile
    const int kg  = lane >> 4;   // k-group (8 bf16 each)

    // ---- Prefetch x fragments (A operand) for BOTH k-chunks; latency hides
    // under the w1 staging loads. 16 VGPR persistent. ----
    bf16x8 af[2][2];
    #pragma unroll
    for (int kc = 0; kc < 2; ++kc) {
        #pragma unroll
        for (int bt = 0; bt < 2; ++bt) {
            int b = bh * 32 + bt * 16 + col;
            const float* xp = x + ((size_t)b * N_TOT + n) * M_DIM + kc * 32 + kg * 8;
            float4 lo = *(const float4*)xp;
            float4 hi = *(const float4*)(xp + 4);
            const float* lp = (const float*)&lo;
            const float* hp = (const float*)&hi;
            union { bf16x8 v; unsigned short s[8]; } cvt;
            #pragma unroll
            for (int j = 0; j < 4; ++j) { cvt.s[j] = f2bf(lp[j]); cvt.s[4 + j] = f2bf(hp[j]); }
            af[kc][bt] = cvt.v;
        }
    }

    f32x4 acc[2][8];
    #pragma unroll
    for (int bt = 0; bt < 2; ++bt)
        #pragma unroll
        for (int ot = 0; ot < 8; ++ot)
            acc[bt][ot] = (f32x4)0.0f;

    // ---- Stage one 32-wide k-chunk of w1 for all 8 neurons into LDS ----
    // unit u: 4 k-rows x 4 n at fixed o; 2048 units = 4 iters x 512 threads.
    auto stage = [&](int kc) {
        #pragma unroll
        for (int it = 0; it < 4; ++it) {
            int u  = it * 512 + tid;
            int n4 = u & 1;
            int o  = (u >> 1) & 127;
            int kq = (u >> 8) & 7;
            int kl = kq * 4;
            const float* gp = w1 + ((size_t)(kc * 32 + kl) * O_DIM + o) * N_TOT + n0 + n4 * 4;
            float4 r0 = *(const float4*)(gp);
            float4 r1 = *(const float4*)(gp + (size_t)O_DIM * N_TOT);
            float4 r2 = *(const float4*)(gp + (size_t)2 * O_DIM * N_TOT);
            float4 r3 = *(const float4*)(gp + (size_t)3 * O_DIM * N_TOT);
            const float* a0 = (const float*)&r0;
            const float* a1 = (const float*)&r1;
            const float* a2 = (const float*)&r2;
            const float* a3 = (const float*)&r3;
            #pragma unroll
            for (int j = 0; j < 4; ++j) {
                int nnw = n4 * 4 + j;
                unsigned short e0 = f2bf(a0[j]);
                unsigned short e1 = f2bf(a1[j]);
                unsigned short e2 = f2bf(a2[j]);
                unsigned short e3 = f2bf(a3[j]);
                unsigned long long pk =
                    (unsigned long long)e0 | ((unsigned long long)e1 << 16) |
                    ((unsigned long long)e2 << 32) | ((unsigned long long)e3 << 48);
                unsigned addr = (unsigned)(nnw * 4096 + o * 32 + kl) * 2u;
                addr ^= ((unsigned)(o >> 1) & 3u) << 4;   // bank swizzle bits 4-5
                *(unsigned long long*)(wlds + addr) = pk;
            }
        }
    };

    // ---- One k-chunk of MFMAs: 8 o-tiles x 2 b-tiles ----
    auto compute = [&](int kc) {
        #pragma unroll
        for (int ot = 0; ot < 8; ++ot) {
            unsigned addr = (unsigned)(nn * 8192 + (ot * 16 + col) * 64 + kg * 16);
            addr ^= ((unsigned)(col >> 1) & 3u) << 4;     // same swizzle (ot*8 & 3 == 0)
            bf16x8 bfrag = *(const bf16x8*)(wlds + addr);
            #pragma unroll
            for (int bt = 0; bt < 2; ++bt)
                acc[bt][ot] = __builtin_amdgcn_mfma_f32_16x16x32_bf16(af[kc][bt], bfrag, acc[bt][ot], 0, 0, 0);
        }
    };

    stage(0);
    __syncthreads();
    compute(0);
    __syncthreads();
    stage(1);
    __syncthreads();
    compute(1);

    // ---- Bias + store: D row = kg*4 + r, col = o; 16-lane x 64B segments ----
    float bv[8];
    #pragma unroll
    for (int ot = 0; ot < 8; ++ot)
        bv[ot] = b1[(size_t)n * O_DIM + ot * 16 + col];

    #pragma unroll
    for (int bt = 0; bt < 2; ++bt) {
        #pragma unroll
        for (int r = 0; r < 4; ++r) {
            int b = bh * 32 + bt * 16 + kg * 4 + r;
            float* op = out + ((size_t)b * N_TOT + n) * O_DIM + col;
            #pragma unroll
            for (int ot = 0; ot < 8; ++ot)
                op[ot * 16] = acc[bt][ot][r] + bv[ot];
        }
    }
}

extern "C" void kernel_launch(void* const* d_in, const int* in_sizes, int n_in,
                              void* d_out, int out_size, void* d_ws, size_t ws_size,
                              hipStream_t stream) {
    const float* x  = (const float*)d_in[0];
    const float* w1 = (const float*)d_in[1];
    const float* b1 = (const float*)d_in[2];
    float* out = (float*)d_out;
    superlinear_mfma<<<dim3(512), dim3(512), 0, stream>>>(x, w1, b1, out);
}